// Round 5
// baseline (181.796 us; speedup 1.0000x reference)
//
#include <hip/hip_runtime.h>
#include <math.h>

#define BB 128
#define TT 1024
#define NN 64
#define NCH 8               // chunks per batch (halved vs r2: phase-2 chain 16->8)
#define SCH 128             // steps per chunk

typedef __attribute__((ext_vector_type(4))) float f32x4;
typedef __attribute__((ext_vector_type(4))) short bf16x4;

__device__ __forceinline__ float wave_sum64(float v) {
#pragma unroll
  for (int o = 32; o > 0; o >>= 1) v += __shfl_xor(v, o, 64);
  return v;
}

// pack two positive f32 into a bf16-pair dword (round-half-up).
// PROVEN bit-exact on this problem (rounds 0-2, absmax 0.0).
// Do NOT replace with v_cvt_pk_bf16_f32: both NaN failures (r3, r4) shared
// that edit; guide (T12/m240) also flags hand-written cvt_pk as a loss.
__device__ __forceinline__ unsigned pkbf(float lo, float hi) {
  unsigned a = __float_as_uint(lo) + 0x8000u;
  unsigned b = __float_as_uint(hi) + 0x8000u;
  return __builtin_amdgcn_perm(b, a, 0x07060302u);
}

__device__ __forceinline__ int fexp(float x) {  // unbiased exponent, 0 for denorm/zero
  unsigned u = __float_as_uint(x);
  int e = (int)((u >> 23) & 0xffu) - 127;
  if ((u & 0x7f800000u) == 0) e = 0;
  return e;
}

// ============================ PHASE 1 + SCORE =============================
// 1056 blocks x 256 threads = 4 INDEPENDENT wave-tasks per workgroup.
// __launch_bounds__(256,4): 128-reg cap (proven no-spill; (256,6) spilled).
// MFMA: 16x16x16bf16_1k (K=16) — the only verified layout for the D->B
// feedback (D layout == B layout identity). K=32 attempt NaN'd (round 3).
// Wave-task tid = blockIdx*4 + wave:
//  tid < 128 : sequence score for batch tid.
//  tid >= 128: idx = tid-128; c = idx>>9 (0..7), b = (idx>>2)&127, g = idx&3.
//    4 waves of one block = 4 col-groups of the SAME (b,c) -> pot loads alias
//    in L1 (FETCH 54.8 -> 17.7 MB measured).
//    Wave evolves 16 cols of H = diag(p_last)·[E^T diag(p)]···E^T over up to
//    SCH=128 steps; renorm cadence (s&7) unchanged from the verified version.
//    Out: Hg[(b*NCH+c)*2048 + (8g+w)*64 + j] = H[row j][cols 16g+2w, 16g+2w+1].
__global__ __launch_bounds__(256, 4) void crf_phase1(
    const float* __restrict__ pot, const int* __restrict__ tags,
    const int* __restrict__ seqlen, const float* __restrict__ K,
    unsigned* __restrict__ Hg, int* __restrict__ Eexp, float* __restrict__ score,
    float* __restrict__ accf, unsigned* __restrict__ cnt) {
  __shared__ __align__(16) float ring[4][4 * 64];   // per-wave px broadcast ring
  __shared__ __align__(16) unsigned sht[4][544];    // per-wave epilogue transpose
  const int wv = threadIdx.x >> 6;
  const int lane = threadIdx.x & 63;
  const int tid = blockIdx.x * 4 + wv;

  if (blockIdx.x == 0 && threadIdx.x == 0) { *accf = 0.0f; *cnt = 0u; }

  if (tid < BB) {
    // ---------------- sequence score (K via L1/L2) ----------------
    const int b = tid;
    const int L = seqlen[b];
    const int* tg = tags + b * TT;
    const float* pbase = pot + (size_t)b * TT * NN;
    float acc = 0.0f;
    for (int t = lane; t < TT; t += 64) {
      if (t < L) {
        int cc = tg[t];
        float u = pbase[(size_t)t * 64 + cc];
        float tr = (t >= 1) ? K[tg[t - 1] * 64 + cc] : 0.0f;
        acc += u + tr;
      }
    }
    acc = wave_sum64(acc);
    if (lane == 0) score[b] = acc;
    return;
  }

  float* const rg = ring[wv];
  unsigned* const shp = sht[wv];

  const int idx = tid - BB;
  const int c = idx >> 9;            // chunk index in HIGH bits (balance)
  const int b = (idx >> 2) & (BB - 1);
  const int g = idx & 3;             // col-group 0..3
  const int L = seqlen[b];
  const int q = lane >> 4, lm = lane & 15;
  const int rb = q * 4;              // this lane's base row within a 16-row k-tile

  const int t0 = c * SCH + 1;
  const int tend = (L < TT) ? L : TT;
  int nsteps = tend - t0;
  if (nsteps > SCH) nsteps = SCH;

  unsigned* Hc = Hg + (size_t)(b * NCH + c) * 2048 + g * 8 * 64;
  if (nsteps <= 0) {  // chunk fully past sequence end -> identity block
#pragma unroll
    for (int w = 0; w < 8; w++) {
      int c0 = g * 16 + 2 * w;
      unsigned v = (lane == c0 ? 0x3F80u : 0u) | (lane == c0 + 1 ? 0x3F800000u : 0u);
      Hc[w * 64 + lane] = v;
    }
    if (lane == 0) Eexp[(b * NCH + c) * 4 + g] = 0;
    return;
  }

  // A-frags: A = E^T, A[m=16mt+lm][k=16kt+4q+i] = exp(K[k*64+m])
  bf16x4 Af[4][4];
#pragma unroll
  for (int mt = 0; mt < 4; mt++)
#pragma unroll
    for (int kt = 0; kt < 4; kt++) {
      float v0 = __expf(K[(kt * 16 + rb + 0) * 64 + mt * 16 + lm]);
      float v1 = __expf(K[(kt * 16 + rb + 1) * 64 + mt * 16 + lm]);
      float v2 = __expf(K[(kt * 16 + rb + 2) * 64 + mt * 16 + lm]);
      float v3 = __expf(K[(kt * 16 + rb + 3) * 64 + mt * 16 + lm]);
      uint2 u; u.x = pkbf(v0, v1); u.y = pkbf(v2, v3);
      Af[mt][kt] = *(bf16x4*)&u;
    }

  // D_init = E^T: D[mt][r] = E^T[16mt+4q+r][16g+lm]
  f32x4 D[4];
#pragma unroll
  for (int mt = 0; mt < 4; mt++) {
    f32x4 d;
#pragma unroll
    for (int r = 0; r < 4; r++)
      d[r] = __expf(K[(g * 16 + lm) * 64 + mt * 16 + rb + r]);
    D[mt] = d;
  }

  // px pipeline: lane j produces exp(pot[t, j]) once; ring slots t mod 4.
  const float* Pj = pot + (size_t)b * TT * NN + lane;
#pragma unroll
  for (int k = 0; k < 3; k++) {  // slots 0..2 = px(t0..t0+2)
    int tt = t0 + k; tt = tt > TT - 1 ? TT - 1 : tt;
    rg[k * 64 + lane] = __expf(Pj[(size_t)tt * NN]);
  }
  int t3 = t0 + 3 > TT - 1 ? TT - 1 : t0 + 3;
  int t4 = t0 + 4 > TT - 1 ? TT - 1 : t0 + 4;
  float rawq0 = Pj[(size_t)t3 * NN];
  float rawq1 = Pj[(size_t)t4 * NN];

  f32x4 pxc[4], pxn[4];
#pragma unroll
  for (int kt = 0; kt < 4; kt++)
    pxc[kt] = *(const f32x4*)&rg[0 * 64 + kt * 16 + rb];

  int etot = 0;
#pragma unroll 2
  for (int s = 0; s < nsteps - 1; s++) {
    if ((s & 7) == 7) {  // periodic exact power-of-2 renorm, folded into pxc
      float d00 = __int_as_float(__builtin_amdgcn_readfirstlane(__float_as_int(D[0][0])));
      int e = fexp(d00);
      float psc = ldexpf(1.0f, -e);
      etot += e;
#pragma unroll
      for (int kt = 0; kt < 4; kt++) pxc[kt] *= psc;
    }
    // B[kt] = bf16(pxc ⊙ D[kt]) — D layout == B layout
    bf16x4 Bf[4];
#pragma unroll
    for (int kt = 0; kt < 4; kt++) {
      f32x4 pr = D[kt] * pxc[kt];
      uint2 u;
      u.x = pkbf(pr[0], pr[1]);
      u.y = pkbf(pr[2], pr[3]);
      Bf[kt] = *(bf16x4*)&u;
    }
    // read px(t+1) for next iter (broadcast, conflict-free)
#pragma unroll
    for (int kt = 0; kt < 4; kt++)
      pxn[kt] = *(const f32x4*)&rg[((s + 1) & 3) * 64 + kt * 16 + rb];
    // produce px(t+3) into ring; refill raw queue with raw(t+5)
    rg[((s + 3) & 3) * 64 + lane] = __expf(rawq0);
    rawq0 = rawq1;
    {
      int tn = t0 + s + 5; tn = tn > TT - 1 ? TT - 1 : tn;
      rawq1 = Pj[(size_t)tn * NN];
    }
    // D = A · B  (E^T · diag(p) · H)
#pragma unroll
    for (int mt = 0; mt < 4; mt++) {
      f32x4 acc = {0.f, 0.f, 0.f, 0.f};
#pragma unroll
      for (int kt = 0; kt < 4; kt++)
        acc = __builtin_amdgcn_mfma_f32_16x16x16bf16_1k(Af[mt][kt], Bf[kt], acc, 0, 0, 0);
      D[mt] = acc;
    }
#pragma unroll
    for (int kt = 0; kt < 4; kt++) pxc[kt] = pxn[kt];
  }

  // epilogue: H = diag(p_last)·D, renorm, transpose out via LDS
  {
    float hf = __int_as_float(
        __builtin_amdgcn_readfirstlane(__float_as_int(D[0][0] * pxc[0][0])));
    int ef = fexp(hf);
    float sc = ldexpf(1.0f, -ef);
    etot += ef;
#pragma unroll
    for (int mt = 0; mt < 4; mt++) {
      f32x4 d = D[mt]; f32x4 pv = pxc[mt];
      int base = lm * 33 + mt * 8 + q * 2;
      shp[base]     = pkbf(d[0] * pv[0] * sc, d[1] * pv[1] * sc);
      shp[base + 1] = pkbf(d[2] * pv[2] * sc, d[3] * pv[3] * sc);
    }
#pragma unroll
    for (int w = 0; w < 8; w++) {
      unsigned short a0 = ((const unsigned short*)(shp + (2 * w) * 33 + (lane >> 1)))[lane & 1];
      unsigned short a1 = ((const unsigned short*)(shp + (2 * w + 1) * 33 + (lane >> 1)))[lane & 1];
      Hc[w * 64 + lane] = (unsigned)a0 | ((unsigned)a1 << 16);
    }
    if (lane == 0) Eexp[(b * NCH + c) * 4 + g] = etot;
  }
}

// ============================ PHASE 2 + REDUCE =============================
// 128 blocks x 256 threads (4 waves, batch b). Wave g owns col-group g:
// per chunk it loads its 8 H-dwords/lane (named double-buffer regs, depth-2
// prefetch), computes partial S_g[j], combines across waves via double-buffered
// LDS + ONE barrier per chunk. NCH=8 -> sequential chunk chain halved vs r2.
// Eexp preloaded once (lanes 0..31 hold the 8x4 entries) served by __shfl;
// alpha broadcast by __shfl from registers.
__global__ __launch_bounds__(256, 4) void crf_phase2(
    const float* __restrict__ pot, const unsigned* __restrict__ Hg,
    const int* __restrict__ Eexp, const float* __restrict__ score,
    const float* __restrict__ wgt, float* __restrict__ accf,
    unsigned* __restrict__ cnt, float* __restrict__ out) {
  __shared__ __align__(16) float sp[2][4 * 64];   // double-buffered partials
  const int g = threadIdx.x >> 6;
  const int j = threadIdx.x & 63;
  const int b = blockIdx.x;

  float a = __expf(pot[(size_t)b * TT * NN + j]);   // alpha (lane j = state j)
  int atot = 0;
  const int ee = Eexp[b * (NCH * 4) + (j & (NCH * 4 - 1))];  // 8 chunks x 4 grp

  const unsigned* Hb = Hg + (size_t)b * NCH * 2048 + g * 8 * 64;
  unsigned u0[8], u1[8];                            // named regs: chunk c, c+1
#pragma unroll
  for (int w = 0; w < 8; w++) u0[w] = Hb[w * 64 + j];
#pragma unroll
  for (int w = 0; w < 8; w++) u1[w] = Hb[2048 + w * 64 + j];

#define CHUNK(cur, c)                                                          \
  do {                                                                         \
    float S = 0.0f;                                                            \
    _Pragma("unroll")                                                          \
    for (int w = 0; w < 8; w++) {                                              \
      float a0 = __shfl(a, 16 * g + 2 * w, 64);                                \
      float a1 = __shfl(a, 16 * g + 2 * w + 1, 64);                            \
      unsigned r = cur[w];                                                     \
      S += __uint_as_float(r << 16) * a0 +                                     \
           __uint_as_float(r & 0xffff0000u) * a1;                              \
    }                                                                          \
    sp[(c) & 1][g * 64 + j] = S;                                               \
    if ((c) + 2 < NCH) { /* depth-2 prefetch into the buffer just consumed */  \
      const unsigned* Hn = Hb + (size_t)((c) + 2) * 2048;                      \
      _Pragma("unroll")                                                        \
      for (int w = 0; w < 8; w++) cur[w] = Hn[w * 64 + j];                     \
    }                                                                          \
    __syncthreads();                                                           \
    int e0 = __shfl(ee, (c) * 4 + 0, 64);                                      \
    int e1 = __shfl(ee, (c) * 4 + 1, 64);                                      \
    int e2 = __shfl(ee, (c) * 4 + 2, 64);                                      \
    int e3 = __shfl(ee, (c) * 4 + 3, 64);                                      \
    int em = max(max(e0, e1), max(e2, e3));                                    \
    float Sc = ldexpf(sp[(c) & 1][0 * 64 + j], e0 - em) +                      \
               ldexpf(sp[(c) & 1][1 * 64 + j], e1 - em) +                      \
               ldexpf(sp[(c) & 1][2 * 64 + j], e2 - em) +                      \
               ldexpf(sp[(c) & 1][3 * 64 + j], e3 - em);                       \
    int er = fexp(__int_as_float(                                              \
        __builtin_amdgcn_readfirstlane(__float_as_int(Sc))));                  \
    a = ldexpf(Sc, -er);                                                       \
    atot += em + er;                                                           \
  } while (0)

  CHUNK(u0, 0);  CHUNK(u1, 1);  CHUNK(u0, 2);  CHUNK(u1, 3);
  CHUNK(u0, 4);  CHUNK(u1, 5);  CHUNK(u0, 6);  CHUNK(u1, 7);
#undef CHUNK

  float ssum = wave_sum64(a);
  if (threadIdx.x == 0) {
    float lognorm = __logf(ssum) + (float)atot * 0.69314718055994530942f;
    float loss = -(score[b] - lognorm) * wgt[b];
    atomicAdd(accf, loss * (1.0f / BB));
    __threadfence();
    unsigned old = atomicAdd(cnt, 1u);
    if (old == BB - 1) out[0] = atomicAdd(accf, 0.0f);
  }
}

// ===================== R1 fallback (ws too small) =====================
__global__ __launch_bounds__(64) void crf_main_fb(
    const float* __restrict__ pot, const int* __restrict__ tags,
    const int* __restrict__ seqlen, const float* __restrict__ K,
    float* __restrict__ ws) {
  __shared__ float sh[4096];
  const int lane = threadIdx.x;
  const int blk = blockIdx.x;
  if (blk < BB) {
    const int b = blk;
    const int L = seqlen[b];
    float Ec[64];
#pragma unroll
    for (int i = 0; i < 64; i++) Ec[i] = __expf(K[i * 64 + lane]);
    const float* pb = pot + (size_t)b * TT * NN + lane;
    float av = __expf(pb[0]);
    int etot = 0;
    sh[lane] = av;
    float pf[8];
#pragma unroll
    for (int k = 0; k < 8; k++) pf[k] = pb[(size_t)(1 + k) * 64];
    for (int t0 = 1; t0 < L; t0 += 8) {
#pragma unroll
      for (int k = 0; k < 8; k++) {
        const int t = t0 + k;
        const float pe = __expf(pf[k]);
        int tn = t + 8; tn = tn > (TT - 1) ? (TT - 1) : tn;
        pf[k] = pb[(size_t)tn * 64];
        const float4* arow = (const float4*)(sh + ((t - 1) & 1) * 64);
        float s[8];
#pragma unroll
        for (int qq = 0; qq < 8; qq++) s[qq] = 0.0f;
#pragma unroll
        for (int qq = 0; qq < 16; qq++) {
          float4 a4 = arow[qq];
          float pr = fmaf(a4.x, Ec[4 * qq + 0], fmaf(a4.y, Ec[4 * qq + 1],
                     fmaf(a4.z, Ec[4 * qq + 2], a4.w * Ec[4 * qq + 3])));
          s[qq & 7] += pr;
        }
        float S = ((s[0] + s[1]) + (s[2] + s[3])) + ((s[4] + s[5]) + (s[6] + s[7]));
        if (t < L) {
          av = S * pe;
          if ((t & 3) == 0) {
            float m0 = __shfl(av, 0, 64);
            int e = ((__float_as_int(m0) >> 23) & 0xff) - 126;
            av = ldexpf(av, -e);
            etot += e;
          }
        }
        sh[(t & 1) * 64 + lane] = av;
      }
    }
    float ssum = wave_sum64(av);
    if (lane == 0) ws[b] = __logf(ssum) + (float)etot * 0.69314718055994530942f;
  } else {
    const int b = blk - BB;
    const int L = seqlen[b];
    for (int i = lane; i < 4096; i += 64) sh[i] = K[i];
    __syncthreads();
    const int* tg = tags + b * TT;
    const float* pbase = pot + (size_t)b * TT * NN;
    float acc = 0.0f;
    for (int t = lane; t < TT; t += 64) {
      if (t < L) {
        int cc = tg[t];
        float u = pbase[(size_t)t * 64 + cc];
        float tr = 0.0f;
        if (t >= 1) tr = sh[tg[t - 1] * 64 + cc];
        acc += u + tr;
      }
    }
    acc = wave_sum64(acc);
    if (lane == 0) ws[BB + b] = acc;
  }
}

__global__ __launch_bounds__(128) void crf_combine_fb(
    const float* __restrict__ ws, const float* __restrict__ wgt,
    float* __restrict__ out) {
  const int i = threadIdx.x;
  float lv = -(ws[BB + i] - ws[i]) * wgt[i];
  lv = wave_sum64(lv);
  __shared__ float p[2];
  if ((i & 63) == 0) p[i >> 6] = lv;
  __syncthreads();
  if (i == 0) out[0] = (p[0] + p[1]) * (1.0f / 128.0f);
}

extern "C" void kernel_launch(void* const* d_in, const int* in_sizes, int n_in,
                              void* d_out, int out_size, void* d_ws, size_t ws_size,
                              hipStream_t stream) {
  const float* pot    = (const float*)d_in[0];
  const int*   tags   = (const int*)d_in[1];
  const int*   seqlen = (const int*)d_in[2];
  const float* K      = (const float*)d_in[3];
  const float* wgt    = (const float*)d_in[4];

  const size_t HG_DW = (size_t)BB * NCH * 2048;  // 8 MB of bf16-pair dwords
  const size_t NEXP  = (size_t)BB * NCH * 4;
  const size_t need  = (HG_DW + NEXP + BB + 2) * 4;

  if (ws_size >= need) {
    unsigned* Hg    = (unsigned*)d_ws;
    int* Eexp       = (int*)(Hg + HG_DW);
    float* score    = (float*)(Eexp + NEXP);
    float* accf     = score + BB;
    unsigned* cntp  = (unsigned*)(accf + 1);
    crf_phase1<<<(BB + BB * NCH * 4) / 4, 256, 0, stream>>>(pot, tags, seqlen, K,
                                                            Hg, Eexp, score, accf,
                                                            cntp);
    crf_phase2<<<BB, 256, 0, stream>>>(pot, Hg, Eexp, score, wgt, accf, cntp,
                                       (float*)d_out);
  } else {
    float* ws = (float*)d_ws;
    crf_main_fb<<<256, 64, 0, stream>>>(pot, tags, seqlen, K, ws);
    crf_combine_fb<<<1, 128, 0, stream>>>(ws, wgt, (float*)d_out);
  }
}

// Round 6
// 161.273 us; speedup vs baseline: 1.1273x; 1.1273x over previous
//
#include <hip/hip_runtime.h>
#include <math.h>

#define BB 128
#define TT 1024
#define NN 64
#define NCH 16              // chunks per batch (r5 proved NCH=8 is worse)
#define SCH 64              // steps per chunk

typedef __attribute__((ext_vector_type(4))) float f32x4;
typedef __attribute__((ext_vector_type(4))) short bf16x4;

__device__ __forceinline__ float wave_sum64(float v) {
#pragma unroll
  for (int o = 32; o > 0; o >>= 1) v += __shfl_xor(v, o, 64);
  return v;
}

// pack two positive f32 into a bf16-pair dword (round-half-up), 3 VALU.
// PROVEN bit-exact on this problem (rounds 0-2, absmax 0.0).
// Do NOT replace with v_cvt_pk_bf16_f32 (both NaN failures r3/r4 shared it).
__device__ __forceinline__ unsigned pkbf(float lo, float hi) {
  unsigned a = __float_as_uint(lo) + 0x8000u;
  unsigned b = __float_as_uint(hi) + 0x8000u;
  return __builtin_amdgcn_perm(b, a, 0x07060302u);
}

// truncating pack, 1 VALU: same byte map as pkbf minus the rounding adds.
// D = [lo.b2, lo.b3, hi.b2, hi.b3] = (bf16)lo | (bf16)hi<<16, trunc-to-zero.
__device__ __forceinline__ unsigned pkt(float lo, float hi) {
  return __builtin_amdgcn_perm(__float_as_uint(hi), __float_as_uint(lo),
                               0x07060302u);
}

__device__ __forceinline__ int fexp(float x) {  // unbiased exponent, 0 for denorm/zero
  unsigned u = __float_as_uint(x);
  int e = (int)((u >> 23) & 0xffu) - 127;
  if ((u & 0x7f800000u) == 0) e = 0;
  return e;
}

// ============================ PHASE 1 + SCORE =============================
// 2080 blocks x 256 threads = 4 INDEPENDENT wave-tasks per workgroup.
// __launch_bounds__(256,4): 128-reg cap (proven no-spill; (256,6) spilled).
// MFMA: 16x16x16bf16_1k (K=16) — the only verified layout for the D->B
// feedback (D layout == B layout identity). K=32 attempt NaN'd (round 3).
// Inner loop: 8-step unrolled fast path (static ring slots, immediate-offset
// pot loads, named px double-buffer, truncating 1-VALU pack) + generic tail.
// VALU/step ~100 -> ~60 (full-residency phase is VALU-throughput-bound).
__global__ __launch_bounds__(256, 4) void crf_phase1(
    const float* __restrict__ pot, const int* __restrict__ tags,
    const int* __restrict__ seqlen, const float* __restrict__ K,
    unsigned* __restrict__ Hg, int* __restrict__ Eexp, float* __restrict__ score,
    float* __restrict__ accf, unsigned* __restrict__ cnt) {
  __shared__ __align__(16) float ring[4][4 * 64];   // per-wave px broadcast ring
  __shared__ __align__(16) unsigned sht[4][544];    // per-wave epilogue transpose
  const int wv = threadIdx.x >> 6;
  const int lane = threadIdx.x & 63;
  const int tid = blockIdx.x * 4 + wv;

  if (blockIdx.x == 0 && threadIdx.x == 0) { *accf = 0.0f; *cnt = 0u; }

  if (tid < BB) {
    // ---------------- sequence score (K via L1/L2) ----------------
    const int b = tid;
    const int L = seqlen[b];
    const int* tg = tags + b * TT;
    const float* pbase = pot + (size_t)b * TT * NN;
    float acc = 0.0f;
    for (int t = lane; t < TT; t += 64) {
      if (t < L) {
        int cc = tg[t];
        float u = pbase[(size_t)t * 64 + cc];
        float tr = (t >= 1) ? K[tg[t - 1] * 64 + cc] : 0.0f;
        acc += u + tr;
      }
    }
    acc = wave_sum64(acc);
    if (lane == 0) score[b] = acc;
    return;
  }

  float* const rg = ring[wv];
  unsigned* const shp = sht[wv];

  const int idx = tid - BB;
  const int c = idx >> 9;            // chunk index in HIGH bits (balance)
  const int b = (idx >> 2) & (BB - 1);
  const int g = idx & 3;             // col-group 0..3
  const int L = seqlen[b];
  const int q = lane >> 4, lm = lane & 15;
  const int rb = q * 4;              // this lane's base row within a 16-row k-tile

  const int t0 = c * SCH + 1;
  const int tend = (L < TT) ? L : TT;
  int nsteps = tend - t0;
  if (nsteps > SCH) nsteps = SCH;

  unsigned* Hc = Hg + (size_t)(b * NCH + c) * 2048 + g * 8 * 64;
  if (nsteps <= 0) {  // chunk fully past sequence end -> identity block
#pragma unroll
    for (int w = 0; w < 8; w++) {
      int c0 = g * 16 + 2 * w;
      unsigned v = (lane == c0 ? 0x3F80u : 0u) | (lane == c0 + 1 ? 0x3F800000u : 0u);
      Hc[w * 64 + lane] = v;
    }
    if (lane == 0) Eexp[(b * NCH + c) * 4 + g] = 0;
    return;
  }

  // A-frags: A = E^T, A[m=16mt+lm][k=16kt+4q+i] = exp(K[k*64+m])
  bf16x4 Af[4][4];
#pragma unroll
  for (int mt = 0; mt < 4; mt++)
#pragma unroll
    for (int kt = 0; kt < 4; kt++) {
      float v0 = __expf(K[(kt * 16 + rb + 0) * 64 + mt * 16 + lm]);
      float v1 = __expf(K[(kt * 16 + rb + 1) * 64 + mt * 16 + lm]);
      float v2 = __expf(K[(kt * 16 + rb + 2) * 64 + mt * 16 + lm]);
      float v3 = __expf(K[(kt * 16 + rb + 3) * 64 + mt * 16 + lm]);
      uint2 u; u.x = pkbf(v0, v1); u.y = pkbf(v2, v3);
      Af[mt][kt] = *(bf16x4*)&u;
    }

  // D_init = E^T: D[mt][r] = E^T[16mt+4q+r][16g+lm]
  f32x4 D[4];
#pragma unroll
  for (int mt = 0; mt < 4; mt++) {
    f32x4 d;
#pragma unroll
    for (int r = 0; r < 4; r++)
      d[r] = __expf(K[(g * 16 + lm) * 64 + mt * 16 + rb + r]);
    D[mt] = d;
  }

  // px pipeline: lane j produces exp(pot[t, j]) once; ring slots t mod 4.
  const float* Pj = pot + (size_t)b * TT * NN + lane;
#pragma unroll
  for (int k = 0; k < 3; k++) {  // slots 0..2 = px(t0..t0+2)
    int tt = t0 + k; tt = tt > TT - 1 ? TT - 1 : tt;
    rg[k * 64 + lane] = __expf(Pj[(size_t)tt * NN]);
  }
  int t3 = t0 + 3 > TT - 1 ? TT - 1 : t0 + 3;
  int t4 = t0 + 4 > TT - 1 ? TT - 1 : t0 + 4;
  float rawq0 = Pj[(size_t)t3 * NN];
  float rawq1 = Pj[(size_t)t4 * NN];

  int etot = 0;
  int s = 0;

  // -------- fast path: 8-step unrolled (s multiple of 8 at entry) --------
  // steps s..s+7 all valid (s+9 <= nsteps) and clamp-free (t0+s+12 <= TT-1).
  f32x4 pxA[4], pxB[4];
#pragma unroll
  for (int kt = 0; kt < 4; kt++)
    pxA[kt] = *(const f32x4*)&rg[0 * 64 + kt * 16 + rb];

  while (s + 9 <= nsteps && t0 + s + 12 <= TT - 1) {
    const float* Ps = Pj + (size_t)(t0 + s) * NN;
#define STEP_F(k, PXC, PXN)                                                    \
    {                                                                          \
      if ((k) == 7) {  /* renorm cadence (global s&7)==7 */                    \
        float d00 = __int_as_float(                                            \
            __builtin_amdgcn_readfirstlane(__float_as_int(D[0][0])));          \
        int e = fexp(d00);                                                     \
        float psc = ldexpf(1.0f, -e);                                          \
        etot += e;                                                             \
        _Pragma("unroll")                                                      \
        for (int kt = 0; kt < 4; kt++) PXC[kt] *= psc;                         \
      }                                                                        \
      bf16x4 Bf[4];                                                            \
      _Pragma("unroll")                                                        \
      for (int kt = 0; kt < 4; kt++) {                                         \
        f32x4 pr = D[kt] * PXC[kt];                                            \
        uint2 u;                                                               \
        u.x = pkt(pr[0], pr[1]);                                               \
        u.y = pkt(pr[2], pr[3]);                                               \
        Bf[kt] = *(bf16x4*)&u;                                                 \
      }                                                                        \
      _Pragma("unroll")                                                        \
      for (int kt = 0; kt < 4; kt++)                                           \
        PXN[kt] = *(const f32x4*)&rg[(((k) + 1) & 3) * 64 + kt * 16 + rb];     \
      rg[(((k) + 3) & 3) * 64 + lane] = __expf(rawq0);                         \
      rawq0 = rawq1;                                                           \
      rawq1 = Ps[(size_t)((k) + 5) * NN];                                      \
      _Pragma("unroll")                                                        \
      for (int mt = 0; mt < 4; mt++) {                                         \
        f32x4 acc = {0.f, 0.f, 0.f, 0.f};                                      \
        _Pragma("unroll")                                                      \
        for (int kt = 0; kt < 4; kt++)                                         \
          acc = __builtin_amdgcn_mfma_f32_16x16x16bf16_1k(Af[mt][kt], Bf[kt],  \
                                                          acc, 0, 0, 0);       \
        D[mt] = acc;                                                           \
      }                                                                        \
    }
    STEP_F(0, pxA, pxB)  STEP_F(1, pxB, pxA)
    STEP_F(2, pxA, pxB)  STEP_F(3, pxB, pxA)
    STEP_F(4, pxA, pxB)  STEP_F(5, pxB, pxA)
    STEP_F(6, pxA, pxB)  STEP_F(7, pxB, pxA)
#undef STEP_F
    s += 8;
  }

  // -------- generic tail (old body verbatim; entered with s%8==0) --------
  f32x4 pxc[4], pxn[4];
#pragma unroll
  for (int kt = 0; kt < 4; kt++) pxc[kt] = pxA[kt];

  for (; s < nsteps - 1; s++) {
    if ((s & 7) == 7) {  // periodic exact power-of-2 renorm, folded into pxc
      float d00 = __int_as_float(__builtin_amdgcn_readfirstlane(__float_as_int(D[0][0])));
      int e = fexp(d00);
      float psc = ldexpf(1.0f, -e);
      etot += e;
#pragma unroll
      for (int kt = 0; kt < 4; kt++) pxc[kt] *= psc;
    }
    bf16x4 Bf[4];
#pragma unroll
    for (int kt = 0; kt < 4; kt++) {
      f32x4 pr = D[kt] * pxc[kt];
      uint2 u;
      u.x = pkt(pr[0], pr[1]);
      u.y = pkt(pr[2], pr[3]);
      Bf[kt] = *(bf16x4*)&u;
    }
#pragma unroll
    for (int kt = 0; kt < 4; kt++)
      pxn[kt] = *(const f32x4*)&rg[((s + 1) & 3) * 64 + kt * 16 + rb];
    rg[((s + 3) & 3) * 64 + lane] = __expf(rawq0);
    rawq0 = rawq1;
    {
      int tn = t0 + s + 5; tn = tn > TT - 1 ? TT - 1 : tn;
      rawq1 = Pj[(size_t)tn * NN];
    }
#pragma unroll
    for (int mt = 0; mt < 4; mt++) {
      f32x4 acc = {0.f, 0.f, 0.f, 0.f};
#pragma unroll
      for (int kt = 0; kt < 4; kt++)
        acc = __builtin_amdgcn_mfma_f32_16x16x16bf16_1k(Af[mt][kt], Bf[kt], acc, 0, 0, 0);
      D[mt] = acc;
    }
#pragma unroll
    for (int kt = 0; kt < 4; kt++) pxc[kt] = pxn[kt];
  }

  // epilogue: H = diag(p_last)·D, renorm, transpose out via LDS
  {
    float hf = __int_as_float(
        __builtin_amdgcn_readfirstlane(__float_as_int(D[0][0] * pxc[0][0])));
    int ef = fexp(hf);
    float sc = ldexpf(1.0f, -ef);
    etot += ef;
#pragma unroll
    for (int mt = 0; mt < 4; mt++) {
      f32x4 d = D[mt]; f32x4 pv = pxc[mt];
      int base = lm * 33 + mt * 8 + q * 2;
      shp[base]     = pkbf(d[0] * pv[0] * sc, d[1] * pv[1] * sc);
      shp[base + 1] = pkbf(d[2] * pv[2] * sc, d[3] * pv[3] * sc);
    }
#pragma unroll
    for (int w = 0; w < 8; w++) {
      unsigned short a0 = ((const unsigned short*)(shp + (2 * w) * 33 + (lane >> 1)))[lane & 1];
      unsigned short a1 = ((const unsigned short*)(shp + (2 * w + 1) * 33 + (lane >> 1)))[lane & 1];
      Hc[w * 64 + lane] = (unsigned)a0 | ((unsigned)a1 << 16);
    }
    if (lane == 0) Eexp[(b * NCH + c) * 4 + g] = etot;
  }
}

// ============================ PHASE 2 + REDUCE =============================
// r2 version verbatim (NCH=16). 128 blocks x 256 threads (4 waves, batch b).
__global__ __launch_bounds__(256, 4) void crf_phase2(
    const float* __restrict__ pot, const unsigned* __restrict__ Hg,
    const int* __restrict__ Eexp, const float* __restrict__ score,
    const float* __restrict__ wgt, float* __restrict__ accf,
    unsigned* __restrict__ cnt, float* __restrict__ out) {
  __shared__ __align__(16) float sp[2][4 * 64];   // double-buffered partials
  const int g = threadIdx.x >> 6;
  const int j = threadIdx.x & 63;
  const int b = blockIdx.x;

  float a = __expf(pot[(size_t)b * TT * NN + j]);   // alpha (lane j = state j)
  int atot = 0;
  const int ee = Eexp[b * 64 + j];                  // 16 chunks x 4 groups

  const unsigned* Hb = Hg + (size_t)b * NCH * 2048 + g * 8 * 64;
  unsigned u0[8], u1[8];                            // named regs: chunk c, c+1
#pragma unroll
  for (int w = 0; w < 8; w++) u0[w] = Hb[w * 64 + j];
#pragma unroll
  for (int w = 0; w < 8; w++) u1[w] = Hb[2048 + w * 64 + j];

#define CHUNK(cur, c)                                                          \
  do {                                                                         \
    float S = 0.0f;                                                            \
    _Pragma("unroll")                                                          \
    for (int w = 0; w < 8; w++) {                                              \
      float a0 = __shfl(a, 16 * g + 2 * w, 64);                                \
      float a1 = __shfl(a, 16 * g + 2 * w + 1, 64);                            \
      unsigned r = cur[w];                                                     \
      S += __uint_as_float(r << 16) * a0 +                                     \
           __uint_as_float(r & 0xffff0000u) * a1;                              \
    }                                                                          \
    sp[(c) & 1][g * 64 + j] = S;                                               \
    if ((c) + 2 < NCH) { /* depth-2 prefetch into the buffer just consumed */  \
      const unsigned* Hn = Hb + (size_t)((c) + 2) * 2048;                      \
      _Pragma("unroll")                                                        \
      for (int w = 0; w < 8; w++) cur[w] = Hn[w * 64 + j];                     \
    }                                                                          \
    __syncthreads();                                                           \
    int e0 = __shfl(ee, (c) * 4 + 0, 64);                                      \
    int e1 = __shfl(ee, (c) * 4 + 1, 64);                                      \
    int e2 = __shfl(ee, (c) * 4 + 2, 64);                                      \
    int e3 = __shfl(ee, (c) * 4 + 3, 64);                                      \
    int em = max(max(e0, e1), max(e2, e3));                                    \
    float Sc = ldexpf(sp[(c) & 1][0 * 64 + j], e0 - em) +                      \
               ldexpf(sp[(c) & 1][1 * 64 + j], e1 - em) +                      \
               ldexpf(sp[(c) & 1][2 * 64 + j], e2 - em) +                      \
               ldexpf(sp[(c) & 1][3 * 64 + j], e3 - em);                       \
    int er = fexp(__int_as_float(                                              \
        __builtin_amdgcn_readfirstlane(__float_as_int(Sc))));                  \
    a = ldexpf(Sc, -er);                                                       \
    atot += em + er;                                                           \
  } while (0)

  CHUNK(u0, 0);  CHUNK(u1, 1);  CHUNK(u0, 2);  CHUNK(u1, 3);
  CHUNK(u0, 4);  CHUNK(u1, 5);  CHUNK(u0, 6);  CHUNK(u1, 7);
  CHUNK(u0, 8);  CHUNK(u1, 9);  CHUNK(u0, 10); CHUNK(u1, 11);
  CHUNK(u0, 12); CHUNK(u1, 13); CHUNK(u0, 14); CHUNK(u1, 15);
#undef CHUNK

  float ssum = wave_sum64(a);
  if (threadIdx.x == 0) {
    float lognorm = __logf(ssum) + (float)atot * 0.69314718055994530942f;
    float loss = -(score[b] - lognorm) * wgt[b];
    atomicAdd(accf, loss * (1.0f / BB));
    __threadfence();
    unsigned old = atomicAdd(cnt, 1u);
    if (old == BB - 1) out[0] = atomicAdd(accf, 0.0f);
  }
}

// ===================== R1 fallback (ws too small) =====================
__global__ __launch_bounds__(64) void crf_main_fb(
    const float* __restrict__ pot, const int* __restrict__ tags,
    const int* __restrict__ seqlen, const float* __restrict__ K,
    float* __restrict__ ws) {
  __shared__ float sh[4096];
  const int lane = threadIdx.x;
  const int blk = blockIdx.x;
  if (blk < BB) {
    const int b = blk;
    const int L = seqlen[b];
    float Ec[64];
#pragma unroll
    for (int i = 0; i < 64; i++) Ec[i] = __expf(K[i * 64 + lane]);
    const float* pb = pot + (size_t)b * TT * NN + lane;
    float av = __expf(pb[0]);
    int etot = 0;
    sh[lane] = av;
    float pf[8];
#pragma unroll
    for (int k = 0; k < 8; k++) pf[k] = pb[(size_t)(1 + k) * 64];
    for (int t0 = 1; t0 < L; t0 += 8) {
#pragma unroll
      for (int k = 0; k < 8; k++) {
        const int t = t0 + k;
        const float pe = __expf(pf[k]);
        int tn = t + 8; tn = tn > (TT - 1) ? (TT - 1) : tn;
        pf[k] = pb[(size_t)tn * 64];
        const float4* arow = (const float4*)(sh + ((t - 1) & 1) * 64);
        float s[8];
#pragma unroll
        for (int qq = 0; qq < 8; qq++) s[qq] = 0.0f;
#pragma unroll
        for (int qq = 0; qq < 16; qq++) {
          float4 a4 = arow[qq];
          float pr = fmaf(a4.x, Ec[4 * qq + 0], fmaf(a4.y, Ec[4 * qq + 1],
                     fmaf(a4.z, Ec[4 * qq + 2], a4.w * Ec[4 * qq + 3])));
          s[qq & 7] += pr;
        }
        float S = ((s[0] + s[1]) + (s[2] + s[3])) + ((s[4] + s[5]) + (s[6] + s[7]));
        if (t < L) {
          av = S * pe;
          if ((t & 3) == 0) {
            float m0 = __shfl(av, 0, 64);
            int e = ((__float_as_int(m0) >> 23) & 0xff) - 126;
            av = ldexpf(av, -e);
            etot += e;
          }
        }
        sh[(t & 1) * 64 + lane] = av;
      }
    }
    float ssum = wave_sum64(av);
    if (lane == 0) ws[b] = __logf(ssum) + (float)etot * 0.69314718055994530942f;
  } else {
    const int b = blk - BB;
    const int L = seqlen[b];
    for (int i = lane; i < 4096; i += 64) sh[i] = K[i];
    __syncthreads();
    const int* tg = tags + b * TT;
    const float* pbase = pot + (size_t)b * TT * NN;
    float acc = 0.0f;
    for (int t = lane; t < TT; t += 64) {
      if (t < L) {
        int cc = tg[t];
        float u = pbase[(size_t)t * 64 + cc];
        float tr = 0.0f;
        if (t >= 1) tr = sh[tg[t - 1] * 64 + cc];
        acc += u + tr;
      }
    }
    acc = wave_sum64(acc);
    if (lane == 0) ws[BB + b] = acc;
  }
}

__global__ __launch_bounds__(128) void crf_combine_fb(
    const float* __restrict__ ws, const float* __restrict__ wgt,
    float* __restrict__ out) {
  const int i = threadIdx.x;
  float lv = -(ws[BB + i] - ws[i]) * wgt[i];
  lv = wave_sum64(lv);
  __shared__ float p[2];
  if ((i & 63) == 0) p[i >> 6] = lv;
  __syncthreads();
  if (i == 0) out[0] = (p[0] + p[1]) * (1.0f / 128.0f);
}

extern "C" void kernel_launch(void* const* d_in, const int* in_sizes, int n_in,
                              void* d_out, int out_size, void* d_ws, size_t ws_size,
                              hipStream_t stream) {
  const float* pot    = (const float*)d_in[0];
  const int*   tags   = (const int*)d_in[1];
  const int*   seqlen = (const int*)d_in[2];
  const float* K      = (const float*)d_in[3];
  const float* wgt    = (const float*)d_in[4];

  const size_t HG_DW = (size_t)BB * NCH * 2048;  // 16 MB of bf16-pair dwords
  const size_t NEXP  = (size_t)BB * NCH * 4;
  const size_t need  = (HG_DW + NEXP + BB + 2) * 4;

  if (ws_size >= need) {
    unsigned* Hg    = (unsigned*)d_ws;
    int* Eexp       = (int*)(Hg + HG_DW);
    float* score    = (float*)(Eexp + NEXP);
    float* accf     = score + BB;
    unsigned* cntp  = (unsigned*)(accf + 1);
    crf_phase1<<<(BB + BB * NCH * 4) / 4, 256, 0, stream>>>(pot, tags, seqlen, K,
                                                            Hg, Eexp, score, accf,
                                                            cntp);
    crf_phase2<<<BB, 256, 0, stream>>>(pot, Hg, Eexp, score, wgt, accf, cntp,
                                       (float*)d_out);
  } else {
    float* ws = (float*)d_ws;
    crf_main_fb<<<256, 64, 0, stream>>>(pot, tags, seqlen, K, ws);
    crf_combine_fb<<<1, 128, 0, stream>>>(ws, wgt, (float*)d_out);
  }
}